// Round 1
// baseline (70.086 us; speedup 1.0000x reference)
//
#include <hip/hip_runtime.h>

// One thread = one sample. Full 16-amplitude complex state lives in registers.
// Algebraic reductions:
//   - embedding RY(pi*tanh(x)) folded with layer0 RY(w) via RY(a)RY(b)=RY(a+b)
//   - product state kept factored through layer0 RZ -> direct tensor build
//   - CNOTs = compile-time register permutations (free)
//   - layer1 RZ dropped (phases don't affect measured probabilities)

#define CNOT_SWAP(cq, tq)                                               \
    {                                                                   \
        const int cm = 8 >> (cq), tm = 8 >> (tq);                       \
        _Pragma("unroll")                                               \
        for (int n = 0; n < 16; ++n)                                    \
            if ((n & cm) && !(n & tm)) {                                \
                int m = n | tm;                                         \
                float tr = re[n]; re[n] = re[m]; re[m] = tr;            \
                float ti = im[n]; im[n] = im[m]; im[m] = ti;            \
            }                                                           \
    }

__global__ __launch_bounds__(256) void qcirc_kernel(
    const float* __restrict__ x, const float* __restrict__ w,
    float* __restrict__ out, int B)
{
    int i = blockIdx.x * blockDim.x + threadIdx.x;
    if (i >= B) return;

    // ---- uniform gate coefficients (half-angle cos/sin); w is [2,4,2] ----
    float Wc[4], Ws[4], Zc[4], Zs[4], C1[4], S1[4];
#pragma unroll
    for (int q = 0; q < 4; ++q) {
        float a = 0.5f * w[2 * q];          // layer0 RY half-angle
        Wc[q] = __cosf(a); Ws[q] = __sinf(a);
        float b = 0.5f * w[2 * q + 1];      // layer0 RZ half-angle
        Zc[q] = __cosf(b); Zs[q] = __sinf(b);
        float c = 0.5f * w[8 + 2 * q];      // layer1 RY half-angle
        C1[q] = __cosf(c); S1[q] = __sinf(c);
        // layer1 RZ: diagonal phases, killed by |amp|^2 -> skipped
    }

    // ---- per-sample angles: x[i, 0..3] ----
    const float4 xv = *reinterpret_cast<const float4*>(x + (size_t)i * 8);
    float xq[4] = {xv.x, xv.y, xv.z, xv.w};

    // per-qubit 1q state after (embed RY + L0 RY + L0 RZ):
    //   alpha = cos(h')*e^{-i z/2},  beta = sin(h')*e^{+i z/2}
    float Ar[4][2], Ai[4][2];
#pragma unroll
    for (int q = 0; q < 4; ++q) {
        float e  = __expf(2.f * xq[q]);
        float t  = 1.f - 2.f * __builtin_amdgcn_rcpf(1.f + e);  // tanh(x)
        float h  = 1.57079632679f * t;                          // (pi*t)/2
        float cc = __cosf(h), sc = __sinf(h);
        float cq = cc * Wc[q] - sc * Ws[q];   // cos(h + w/2)
        float sq = sc * Wc[q] + cc * Ws[q];   // sin(h + w/2)
        Ar[q][0] = cq * Zc[q]; Ai[q][0] = -cq * Zs[q];
        Ar[q][1] = sq * Zc[q]; Ai[q][1] =  sq * Zs[q];
    }

    // ---- tensor product -> 16 complex amplitudes (qubit0 = MSB) ----
    float t01r[4], t01i[4], t23r[4], t23i[4];
#pragma unroll
    for (int a = 0; a < 2; ++a)
#pragma unroll
        for (int b = 0; b < 2; ++b) {
            int j = a * 2 + b;
            t01r[j] = Ar[0][a] * Ar[1][b] - Ai[0][a] * Ai[1][b];
            t01i[j] = Ar[0][a] * Ai[1][b] + Ai[0][a] * Ar[1][b];
            t23r[j] = Ar[2][a] * Ar[3][b] - Ai[2][a] * Ai[3][b];
            t23i[j] = Ar[2][a] * Ai[3][b] + Ai[2][a] * Ar[3][b];
        }

    float re[16], im[16];
#pragma unroll
    for (int n = 0; n < 16; ++n) {
        int hi = n >> 2, lo = n & 3;
        re[n] = t01r[hi] * t23r[lo] - t01i[hi] * t23i[lo];
        im[n] = t01r[hi] * t23i[lo] + t01i[hi] * t23r[lo];
    }

    // ---- layer0 entangler ----
    CNOT_SWAP(0, 1); CNOT_SWAP(1, 2); CNOT_SWAP(2, 3); CNOT_SWAP(3, 0);

    // ---- layer1 RY (uniform coefficients) ----
#pragma unroll
    for (int q = 0; q < 4; ++q) {
        const int mask = 8 >> q;
        const float c = C1[q], s = S1[q];
#pragma unroll
        for (int n = 0; n < 16; ++n)
            if (!(n & mask)) {
                int m = n | mask;
                float r0 = re[n], r1 = re[m];
                float i0 = im[n], i1 = im[m];
                re[n] = c * r0 - s * r1;  re[m] = s * r0 + c * r1;
                im[n] = c * i0 - s * i1;  im[m] = s * i0 + c * i1;
            }
    }

    // ---- layer1 entangler (layer1 RZ already dropped) ----
    CNOT_SWAP(0, 1); CNOT_SWAP(1, 2); CNOT_SWAP(2, 3); CNOT_SWAP(3, 0);

    // ---- measurement: z_q = P(bit_q=0) - P(bit_q=1) ----
    float p[16];
#pragma unroll
    for (int n = 0; n < 16; ++n) p[n] = re[n] * re[n] + im[n] * im[n];

    float total = 0.f;
#pragma unroll
    for (int n = 0; n < 16; ++n) total += p[n];

    float z[4];
#pragma unroll
    for (int q = 0; q < 4; ++q) {
        const int mask = 8 >> q;
        float s1 = 0.f;
#pragma unroll
        for (int n = 0; n < 16; ++n)
            if (n & mask) s1 += p[n];
        z[q] = total - 2.f * s1;
    }

    *reinterpret_cast<float4*>(out + (size_t)i * 4) =
        make_float4(z[0], z[1], z[2], z[3]);
}

extern "C" void kernel_launch(void* const* d_in, const int* in_sizes, int n_in,
                              void* d_out, int out_size, void* d_ws, size_t ws_size,
                              hipStream_t stream) {
    const float* x = (const float*)d_in[0];
    const float* w = (const float*)d_in[1];
    float* out = (float*)d_out;
    const int B = in_sizes[0] / 8;          // 524288
    const int threads = 256;
    const int blocks = (B + threads - 1) / threads;
    hipLaunchKernelGGL(qcirc_kernel, dim3(blocks), dim3(threads), 0, stream,
                       x, w, out, B);
}